// Round 6
// baseline (152.416 us; speedup 1.0000x reference)
//
#include <hip/hip_runtime.h>
#include <stdint.h>

// ClusterHead: P = softmax_k( x . c_k - 0.5*||c_k||^2 )   (||x||^2 cancels)
// Split-bf16: x.c = x_hi.c_hi + x_lo.c_hi + x_hi.c_lo.
// R6: m201-style counted-vmcnt pipeline. 4x32KB LDS B-ring, prefetch
// distance 3 sub-images; in-loop waits vmcnt(8/9/8/8) -- NEVER drain to 0.
// setprio(1) around MFMA clusters. 1 block/CU (register-capped), 8 waves.
//
// FIFO accounting (4 loads per B-stage, x is 1 plain load):
//  enter J0: inflight [s0+1, s0+2] (8)
//  J0: stage s0+3 -> 12;  end fence vmcnt(8)  (drains s0+1)
//  J1: load x(t+1), stage s0+4 -> 13; end fence vmcnt(9) (drains s0+2; x safe
//      either side of the stage: vmcnt(9) leaves {s0+3,s0+4,x} or {s0+3,x,s0+4})
//  J2: CONVERT x (compiler auto-wait), stage s0+5; end fence vmcnt(8)
//  J3: stage s0+6 -> 12; end fence vmcnt(8) (drains s0+4) -> invariant restored.

namespace {
constexpr int N_ROWS  = 32768;
constexpr int K_CL    = 1024;
constexpr int D_DIM   = 512;
constexpr int BM      = 64;
constexpr int THREADS = 512;
constexpr int WAVES   = 8;
constexpr int NSLICE  = 16;     // k-slices of 32
}

typedef __bf16 bf16_t;
typedef __bf16 bf16x8 __attribute__((ext_vector_type(8)));
typedef __bf16 bf16x4 __attribute__((ext_vector_type(4)));
typedef float  f32x4  __attribute__((ext_vector_type(4)));

__device__ inline void async_copy16(const void* g, void* l) {
  __builtin_amdgcn_global_load_lds(
      (const __attribute__((address_space(1))) uint32_t*)g,
      (__attribute__((address_space(3))) uint32_t*)l, 16, 0, 0);
}

// ---- prep: bpack sub-images [s][g][col] 16B chunks (k-major)
// sub-image s = 4*t + j : j0/j1 = c_hi cols 0-511 / 512-1023, j2/j3 = c_lo halves.
__global__ __launch_bounds__(64) void prep_kernel(const float* __restrict__ centers,
                                                  bf16_t* __restrict__ bpack,
                                                  float* __restrict__ bias) {
  const int col = blockIdx.x, lane = threadIdx.x;
  const int t = lane >> 2, g = lane & 3;   // lane owns d in [lane*8, lane*8+8)
  const float* src = centers + (size_t)col * D_DIM + lane * 8;
  bf16x8 hi, lo;
  float ssq = 0.f;
  #pragma unroll
  for (int i = 0; i < 8; ++i) {
    float v = src[i];
    ssq += v * v;
    bf16_t h = (bf16_t)v;
    hi[i] = h;
    lo[i] = (bf16_t)(v - (float)h);
  }
  const int jh = col >> 9, c = col & 511;
  *(bf16x8*)(bpack + ((size_t)(4 * t + jh)     * 2048 + g * 512 + c) * 8) = hi;
  *(bf16x8*)(bpack + ((size_t)(4 * t + 2 + jh) * 2048 + g * 512 + c) * 8) = lo;
  for (int off = 32; off; off >>= 1) ssq += __shfl_down(ssq, off, 64);
  if (lane == 0) bias[col] = -0.5f * ssq;
}

// ---- main fused kernel: 64 rows x 1024 cols per block ----
__global__ __launch_bounds__(THREADS, 2) void cluster_kernel(
    const float* __restrict__ x, const bf16_t* __restrict__ bpack,
    const float* __restrict__ bias, float* __restrict__ out) {
  __shared__ bf16_t Bbuf[4][16384];     // 128KB ring; sub-image s -> Bbuf[s&3]
  __shared__ bf16_t Abuf[2][2][2048];   // 16KB [slice parity][hi/lo]
  __shared__ float  red[WAVES * BM];    // 2KB
  __shared__ float  fin[BM];

  const int tid  = threadIdx.x;
  const int wid  = tid >> 6;
  const int lane = tid & 63;
  const int g    = lane >> 4;
  const int l15  = lane & 15;
  const int brow = blockIdx.x * BM;
  const int xrow = tid >> 3, q = tid & 7, gk = q >> 1, qh = q & 1;

  f32x4 acc[4][8];
  #pragma unroll
  for (int rb = 0; rb < 4; ++rb)
    #pragma unroll
    for (int cc = 0; cc < 8; ++cc) acc[rb][cc] = (f32x4){0.f, 0.f, 0.f, 0.f};

#define STAGE_B(S)                                                             \
  {                                                                            \
    const char* gs_ = (const char*)bpack + (size_t)((S) & 63) * 32768 +        \
                      wid * 4096 + lane * 16;                                  \
    char* ld_ = (char*)&Bbuf[(S) & 3][0] + wid * 4096;                         \
    _Pragma("unroll")                                                          \
    for (int i_ = 0; i_ < 4; ++i_)                                             \
      async_copy16(gs_ + i_ * 1024, ld_ + i_ * 1024);                          \
  }
#define CONVERT(XV, PAR)                                                       \
  {                                                                            \
    bf16x4 h4_, l4_;                                                           \
    float vv_[4] = {(XV).x, (XV).y, (XV).z, (XV).w};                           \
    _Pragma("unroll")                                                          \
    for (int i_ = 0; i_ < 4; ++i_) {                                           \
      bf16_t h_ = (bf16_t)vv_[i_];                                             \
      h4_[i_] = h_;                                                            \
      l4_[i_] = (bf16_t)(vv_[i_] - (float)h_);                                 \
    }                                                                          \
    *(bf16x4*)&Abuf[(PAR)][0][(gk * 64 + xrow) * 8 + qh * 4] = h4_;            \
    *(bf16x4*)&Abuf[(PAR)][1][(gk * 64 + xrow) * 8 + qh * 4] = l4_;            \
  }
#define COMPUTE(BUF, HALF, WITH_LO)                                            \
  {                                                                            \
    const bf16_t* bb = &Bbuf[(BUF)][0];                                        \
    bf16x8 bfrag[4];                                                           \
    _Pragma("unroll")                                                          \
    for (int cb = 0; cb < 4; ++cb)                                             \
      bfrag[cb] = *(const bf16x8*)&bb[(g * 512 + wid * 64 + cb * 16 + l15) * 8]; \
    __builtin_amdgcn_s_setprio(1);                                             \
    _Pragma("unroll")                                                          \
    for (int cb = 0; cb < 4; ++cb) {                                           \
      _Pragma("unroll")                                                        \
      for (int rb = 0; rb < 4; ++rb)                                           \
        acc[rb][(HALF) * 4 + cb] = __builtin_amdgcn_mfma_f32_16x16x32_bf16(    \
            ahi[rb], bfrag[cb], acc[rb][(HALF) * 4 + cb], 0, 0, 0);            \
      if (WITH_LO) {                                                           \
        _Pragma("unroll")                                                      \
        for (int rb = 0; rb < 4; ++rb)                                         \
          acc[rb][(HALF) * 4 + cb] = __builtin_amdgcn_mfma_f32_16x16x32_bf16(  \
              alo[rb], bfrag[cb], acc[rb][(HALF) * 4 + cb], 0, 0, 0);          \
      }                                                                        \
    }                                                                          \
    __builtin_amdgcn_s_setprio(0);                                             \
  }
#define FENCE(VMSTR)                                                           \
    asm volatile(VMSTR ::: "memory");                                          \
    __builtin_amdgcn_s_barrier();                                              \
    __builtin_amdgcn_sched_barrier(0);

  const float* xbase = x + (size_t)(brow + xrow) * D_DIM + q * 4;

  // ---- prologue: B(0..2) in flight, x(0) -> convert ----
  STAGE_B(0)
  STAGE_B(1)
  STAGE_B(2)
  __builtin_amdgcn_sched_barrier(0);
  {
    float4 xv0 = *(const float4*)xbase;   // newest in FIFO; compiler auto-waits
    CONVERT(xv0, 0)
  }
  FENCE("s_waitcnt vmcnt(8) lgkmcnt(0)")   // B(0) done; B(1),B(2) in flight

  bf16x8 ahi[4], alo[4];

  // ---- main loop: 16 slices x 4 sub-iters ----
  #pragma unroll 1
  for (int t = 0; t < NSLICE; ++t) {
    const int s0 = 4 * t;

    // J0: compute B[0]=s0 (hi/h0, A hi+lo); stage s0+3
    STAGE_B(s0 + 3)
    __builtin_amdgcn_sched_barrier(0);
    #pragma unroll
    for (int rb = 0; rb < 4; ++rb) {
      ahi[rb] = *(const bf16x8*)&Abuf[t & 1][0][(g * 64 + rb * 16 + l15) * 8];
      alo[rb] = *(const bf16x8*)&Abuf[t & 1][1][(g * 64 + rb * 16 + l15) * 8];
    }
    COMPUTE(0, 0, 1)
    FENCE("s_waitcnt vmcnt(8) lgkmcnt(0)")

    // J1: compute B[1] (hi/h1, A hi+lo); issue x(t+1); stage s0+4
    float4 xv = *(const float4*)(xbase + ((t + 1) & 15) * 32);
    STAGE_B(s0 + 4)
    __builtin_amdgcn_sched_barrier(0);
    COMPUTE(1, 1, 1)
    FENCE("s_waitcnt vmcnt(9) lgkmcnt(0)")

    // J2: convert x(t+1); compute B[2] (lo/h0, A hi); stage s0+5
    CONVERT(xv, (t + 1) & 1)
    STAGE_B(s0 + 5)
    __builtin_amdgcn_sched_barrier(0);
    COMPUTE(2, 0, 0)
    FENCE("s_waitcnt vmcnt(8) lgkmcnt(0)")

    // J3: compute B[3] (lo/h1, A hi); stage s0+6
    STAGE_B(s0 + 6)
    __builtin_amdgcn_sched_barrier(0);
    COMPUTE(3, 1, 0)
    FENCE("s_waitcnt vmcnt(8) lgkmcnt(0)")
  }

  __syncthreads();   // full drain (incl. dangling wrapped stages)

  // ---- epilogue: fused softmax over 1024 columns ----
  // col(cc) = (cc>>2)*512 + wid*64 + (cc&3)*16 + l15 ; row = rb*16 + g*4 + j
  float bcol[8];
  #pragma unroll
  for (int cc = 0; cc < 8; ++cc)
    bcol[cc] = bias[(cc >> 2) * 512 + wid * 64 + (cc & 3) * 16 + l15];

  float rmax[4][4];
  #pragma unroll
  for (int rb = 0; rb < 4; ++rb) {
    #pragma unroll
    for (int j = 0; j < 4; ++j) {
      float m = -3.0e38f;
      #pragma unroll
      for (int cc = 0; cc < 8; ++cc) {
        float v = acc[rb][cc][j] + bcol[cc];
        acc[rb][cc][j] = v;
        m = fmaxf(m, v);
      }
      m = fmaxf(m, __shfl_xor(m, 1, 64));
      m = fmaxf(m, __shfl_xor(m, 2, 64));
      m = fmaxf(m, __shfl_xor(m, 4, 64));
      m = fmaxf(m, __shfl_xor(m, 8, 64));
      rmax[rb][j] = m;
    }
  }
  if (l15 == 0) {
    #pragma unroll
    for (int rb = 0; rb < 4; ++rb)
      #pragma unroll
      for (int j = 0; j < 4; ++j)
        red[wid * BM + rb * 16 + g * 4 + j] = rmax[rb][j];
  }
  __syncthreads();
  if (tid < BM) {
    float m = red[tid];
    #pragma unroll
    for (int w = 1; w < WAVES; ++w) m = fmaxf(m, red[w * BM + tid]);
    fin[tid] = m;
  }
  __syncthreads();

  #pragma unroll
  for (int rb = 0; rb < 4; ++rb) {
    #pragma unroll
    for (int j = 0; j < 4; ++j) {
      float m = fin[rb * 16 + g * 4 + j];
      float s = 0.f;
      #pragma unroll
      for (int cc = 0; cc < 8; ++cc) {
        float e = __expf(acc[rb][cc][j] - m);
        acc[rb][cc][j] = e;
        s += e;
      }
      s += __shfl_xor(s, 1, 64);
      s += __shfl_xor(s, 2, 64);
      s += __shfl_xor(s, 4, 64);
      s += __shfl_xor(s, 8, 64);
      rmax[rb][j] = s;
    }
  }
  __syncthreads();
  if (l15 == 0) {
    #pragma unroll
    for (int rb = 0; rb < 4; ++rb)
      #pragma unroll
      for (int j = 0; j < 4; ++j)
        red[wid * BM + rb * 16 + g * 4 + j] = rmax[rb][j];
  }
  __syncthreads();
  if (tid < BM) {
    float s = 0.f;
    #pragma unroll
    for (int w = 0; w < WAVES; ++w) s += red[w * BM + tid];
    fin[tid] = 1.0f / s;
  }
  __syncthreads();

  #pragma unroll
  for (int rb = 0; rb < 4; ++rb) {
    #pragma unroll
    for (int j = 0; j < 4; ++j) {
      const int row = rb * 16 + g * 4 + j;
      const float rs = fin[row];
      #pragma unroll
      for (int cc = 0; cc < 8; ++cc) {
        const int col = (cc >> 2) * 512 + wid * 64 + (cc & 3) * 16 + l15;
        out[(size_t)(brow + row) * K_CL + col] = acc[rb][cc][j] * rs;
      }
    }
  }
}

extern "C" void kernel_launch(void* const* d_in, const int* in_sizes, int n_in,
                              void* d_out, int out_size, void* d_ws, size_t ws_size,
                              hipStream_t stream) {
  const float* x       = (const float*)d_in[0];   // [32768, 512] fp32
  const float* centers = (const float*)d_in[1];   // [1024, 512] fp32
  float* out = (float*)d_out;                     // [32768, 1024] fp32

  bf16_t* bpack = (bf16_t*)d_ws;                                 // 64*32KB = 2MB
  float*  bias  = (float*)((char*)d_ws + (size_t)64 * 32768);    // 4KB

  prep_kernel<<<K_CL, 64, 0, stream>>>(centers, bpack, bias);
  cluster_kernel<<<N_ROWS / BM, THREADS, 0, stream>>>(x, bpack, bias, out);
}

// Round 7
// 123.383 us; speedup vs baseline: 1.2353x; 1.2353x over previous
//
#include <hip/hip_runtime.h>
#include <stdint.h>

// ClusterHead: P = softmax_k( x . c_k - 0.5*||c_k||^2 )   (||x||^2 cancels)
// R7: fp16 split, TWO terms: logits ~= x_h . (c_h + c_l), x_h = fp16(x),
// c_h = fp16(c), c_l = fp16(c - c_h). Dropped x_l.c term ~ 4e-3 logit rms ->
// prob error ~0.01 < 0.02 threshold. 32x32x16 f16 MFMA (2178 TF ceiling,
// 3x fewer instructions than 16x16x32). Structure = R5 (best measured):
// B global->VGPR reg double-buffer, A in LDS ping-pong, 1 barrier/slice,
// no manual vmcnt/sched pinning (R6 showed pinning regresses).
//
// B-pack layout (built by prep): 64 sub-images of 32KB; sub-image s:
//   s = 4t + jh      : c_hi, k-slice t, column half jh (512 cols)
//   s = 4t + 2 + jh  : c_lo
// within: [ks(2)][cb(16)][ (c32*2 + kh)*16B + e*2 ]  (1KB per (ks,cb) block,
// lane l reads chunk (l&31)*2+(l>>5) -> full 1KB per wave, coalesced).
// MFMA 32x32x16 f16 operand layout: A/B lane l: row/col = l&31,
// k = (l>>5)*8 + e; C/D: col = l&31, row = (reg&3) + 8*(reg>>2) + 4*(l>>5).

namespace {
constexpr int N_ROWS  = 32768;
constexpr int K_CL    = 1024;
constexpr int D_DIM   = 512;
constexpr int BM      = 64;
constexpr int THREADS = 512;
constexpr int WAVES   = 8;
constexpr int NSLICE  = 16;     // k-slices of 32
}

typedef _Float16 f16_t;
typedef _Float16 f16x8 __attribute__((ext_vector_type(8)));
typedef _Float16 f16x4 __attribute__((ext_vector_type(4)));
typedef float    f32x16 __attribute__((ext_vector_type(16)));

// ---- prep: fp16 hi/lo B-pack + bias = -0.5*||c||^2 (fp32 exact)
__global__ __launch_bounds__(64) void prep_kernel(const float* __restrict__ centers,
                                                  f16_t* __restrict__ bpack,
                                                  float* __restrict__ bias) {
  const int col = blockIdx.x, lane = threadIdx.x;
  const int t  = lane >> 2;          // k-slice of this lane's 8 d's
  const int ks = (lane >> 1) & 1;    // 16-k group
  const int kh = lane & 1;           // 8-k half
  const float* src = centers + (size_t)col * D_DIM + lane * 8;
  f16x8 hi, lo;
  float ssq = 0.f;
  #pragma unroll
  for (int i = 0; i < 8; ++i) {
    float v = src[i];
    ssq += v * v;
    f16_t h = (f16_t)v;
    hi[i] = h;
    lo[i] = (f16_t)(v - (float)h);
  }
  const int jh = col >> 9, cb = (col & 511) >> 5, c32 = col & 31;
  const size_t off = ((size_t)ks * 16 + cb) * 512 + (c32 * 2 + kh) * 8;  // halfwords
  *(f16x8*)(bpack + (size_t)(4 * t + jh)     * 16384 + off) = hi;
  *(f16x8*)(bpack + (size_t)(4 * t + 2 + jh) * 16384 + off) = lo;
  for (int o = 32; o; o >>= 1) ssq += __shfl_down(ssq, o, 64);
  if (lane == 0) bias[col] = -0.5f * ssq;
}

// ---- main fused kernel: 64 rows x 1024 cols per block ----
__global__ __launch_bounds__(THREADS, 2) void cluster_kernel(
    const float* __restrict__ x, const f16_t* __restrict__ bpack,
    const float* __restrict__ bias, float* __restrict__ out) {
  __shared__ f16_t Abuf[2][4][64][8];   // [slice parity][kh2][row][e]  8KB
  __shared__ float red[WAVES * BM];     // 2KB
  __shared__ float fin[BM];

  const int tid  = threadIdx.x;
  const int wid  = tid >> 6;
  const int lane = tid & 63;
  const int l31  = lane & 31;
  const int h    = lane >> 5;
  const int brow = blockIdx.x * BM;
  const int xrow = tid >> 3, q8 = tid & 7;

  f32x16 acc[2][4];
  #pragma unroll
  for (int rb = 0; rb < 2; ++rb)
    #pragma unroll
    for (int cc = 0; cc < 4; ++cc)
      #pragma unroll
      for (int e = 0; e < 16; ++e) acc[rb][cc][e] = 0.f;

  // per-lane byte base into a sub-image (wave's 2 col-blocks start at wid*2048)
  const char* bbase = (const char*)bpack + wid * 2048 + (l31 * 2 + h) * 16;
  const float* xbase = x + (size_t)(brow + xrow) * D_DIM + q8 * 4;

#define LOADB(S, DST)                                                          \
  {                                                                            \
    const char* p_ = bbase + (size_t)((S) & 63) * 32768;                       \
    (DST)[0] = *(const f16x8*)(p_);            /* ks0, cb even */              \
    (DST)[1] = *(const f16x8*)(p_ + 1024);     /* ks0, cb odd  */              \
    (DST)[2] = *(const f16x8*)(p_ + 16384);    /* ks1, cb even */              \
    (DST)[3] = *(const f16x8*)(p_ + 17408);    /* ks1, cb odd  */              \
  }
#define CONVERT(XV, PAR)                                                       \
  {                                                                            \
    f16x4 h4_;                                                                 \
    h4_[0] = (f16_t)(XV).x; h4_[1] = (f16_t)(XV).y;                            \
    h4_[2] = (f16_t)(XV).z; h4_[3] = (f16_t)(XV).w;                            \
    *(f16x4*)&Abuf[(PAR)][q8 >> 1][xrow][(q8 & 1) * 4] = h4_;                  \
  }
#define COMPUTE(B, JH)                                                         \
  {                                                                            \
    _Pragma("unroll")                                                          \
    for (int ks_ = 0; ks_ < 2; ++ks_)                                          \
      _Pragma("unroll")                                                        \
      for (int c2_ = 0; c2_ < 2; ++c2_) {                                      \
        _Pragma("unroll")                                                      \
        for (int rb_ = 0; rb_ < 2; ++rb_)                                      \
          acc[rb_][(JH) * 2 + c2_] = __builtin_amdgcn_mfma_f32_32x32x16_f16(   \
              a[rb_][ks_], (B)[ks_ * 2 + c2_], acc[rb_][(JH) * 2 + c2_],       \
              0, 0, 0);                                                        \
      }                                                                        \
  }

  f16x8 bcur[4], bnxt[4];

  // ---- prologue: convert x slice 0, prefetch B(0) ----
  {
    float4 xv0 = *(const float4*)xbase;
    CONVERT(xv0, 0)
  }
  LOADB(0, bcur)
  __syncthreads();

  f16x8 a[2][2];

  // ---- main loop: 16 slices x 4 sub-images, barrier once per slice ----
  #pragma unroll 1
  for (int t = 0; t < NSLICE; ++t) {
    #pragma unroll
    for (int rb = 0; rb < 2; ++rb)
      #pragma unroll
      for (int ks = 0; ks < 2; ++ks)
        a[rb][ks] = *(const f16x8*)&Abuf[t & 1][ks * 2 + h][rb * 32 + l31][0];

    const int s0 = 4 * t;

    // J0: c_hi half0
    LOADB(s0 + 1, bnxt)
    float4 xv = *(const float4*)(xbase + ((t + 1) & 15) * 32);
    COMPUTE(bcur, 0)

    // J1: c_hi half1
    LOADB(s0 + 2, bcur)
    COMPUTE(bnxt, 1)

    // J2: c_lo half0; convert x(t+1)
    LOADB(s0 + 3, bnxt)
    CONVERT(xv, (t + 1) & 1)
    COMPUTE(bcur, 0)

    // J3: c_lo half1; prefetch next slice (wrapped dummy at tail)
    LOADB((s0 + 4) & 63, bcur)
    COMPUTE(bnxt, 1)

    __syncthreads();   // A(t+1) visible; bounds wave skew
  }

  // ---- epilogue: fused softmax over 1024 columns ----
  // col(cc) = (cc>>1)*512 + wid*64 + (cc&1)*32 + l31
  // row(rb,reg) = rb*32 + (reg&3) + 8*(reg>>2) + 4*h
  float bcol[4];
  #pragma unroll
  for (int cc = 0; cc < 4; ++cc)
    bcol[cc] = bias[(cc >> 1) * 512 + wid * 64 + (cc & 1) * 32 + l31];

  float rr[2][16];
  #pragma unroll
  for (int rb = 0; rb < 2; ++rb)
    #pragma unroll
    for (int reg = 0; reg < 16; ++reg) {
      float m = -3.0e38f;
      #pragma unroll
      for (int cc = 0; cc < 4; ++cc) {
        float v = acc[rb][cc][reg] + bcol[cc];
        acc[rb][cc][reg] = v;
        m = fmaxf(m, v);
      }
      m = fmaxf(m, __shfl_xor(m, 1, 64));
      m = fmaxf(m, __shfl_xor(m, 2, 64));
      m = fmaxf(m, __shfl_xor(m, 4, 64));
      m = fmaxf(m, __shfl_xor(m, 8, 64));
      m = fmaxf(m, __shfl_xor(m, 16, 64));
      rr[rb][reg] = m;
    }
  if (l31 == 0) {
    #pragma unroll
    for (int rb = 0; rb < 2; ++rb)
      #pragma unroll
      for (int reg = 0; reg < 16; ++reg)
        red[wid * BM + rb * 32 + (reg & 3) + 8 * (reg >> 2) + 4 * h] = rr[rb][reg];
  }
  __syncthreads();
  if (tid < BM) {
    float m = red[tid];
    #pragma unroll
    for (int w = 1; w < WAVES; ++w) m = fmaxf(m, red[w * BM + tid]);
    fin[tid] = m;
  }
  __syncthreads();

  #pragma unroll
  for (int rb = 0; rb < 2; ++rb)
    #pragma unroll
    for (int reg = 0; reg < 16; ++reg) {
      const float m = fin[rb * 32 + (reg & 3) + 8 * (reg >> 2) + 4 * h];
      float s = 0.f;
      #pragma unroll
      for (int cc = 0; cc < 4; ++cc) {
        float e = __expf(acc[rb][cc][reg] - m);
        acc[rb][cc][reg] = e;
        s += e;
      }
      s += __shfl_xor(s, 1, 64);
      s += __shfl_xor(s, 2, 64);
      s += __shfl_xor(s, 4, 64);
      s += __shfl_xor(s, 8, 64);
      s += __shfl_xor(s, 16, 64);
      rr[rb][reg] = s;
    }
  __syncthreads();   // fin(max) reads done before red overwrite
  if (l31 == 0) {
    #pragma unroll
    for (int rb = 0; rb < 2; ++rb)
      #pragma unroll
      for (int reg = 0; reg < 16; ++reg)
        red[wid * BM + rb * 32 + (reg & 3) + 8 * (reg >> 2) + 4 * h] = rr[rb][reg];
  }
  __syncthreads();
  if (tid < BM) {
    float s = 0.f;
    #pragma unroll
    for (int w = 0; w < WAVES; ++w) s += red[w * BM + tid];
    fin[tid] = 1.0f / s;
  }
  __syncthreads();

  #pragma unroll
  for (int rb = 0; rb < 2; ++rb)
    #pragma unroll
    for (int reg = 0; reg < 16; ++reg) {
      const int row = rb * 32 + (reg & 3) + 8 * (reg >> 2) + 4 * h;
      const float rs = fin[row];
      #pragma unroll
      for (int cc = 0; cc < 4; ++cc) {
        const int col = (cc >> 1) * 512 + wid * 64 + (cc & 1) * 32 + l31;
        out[(size_t)(brow + row) * K_CL + col] = acc[rb][cc][reg] * rs;
      }
    }
}

extern "C" void kernel_launch(void* const* d_in, const int* in_sizes, int n_in,
                              void* d_out, int out_size, void* d_ws, size_t ws_size,
                              hipStream_t stream) {
  const float* x       = (const float*)d_in[0];   // [32768, 512] fp32
  const float* centers = (const float*)d_in[1];   // [1024, 512] fp32
  float* out = (float*)d_out;                     // [32768, 1024] fp32

  f16_t* bpack = (f16_t*)d_ws;                                   // 64*32KB = 2MB
  float* bias  = (float*)((char*)d_ws + (size_t)64 * 32768);     // 4KB

  prep_kernel<<<K_CL, 64, 0, stream>>>(centers, bpack, bias);
  cluster_kernel<<<N_ROWS / BM, THREADS, 0, stream>>>(x, bpack, bias, out);
}